// Round 8
// baseline (166.542 us; speedup 1.0000x reference)
//
#include <hip/hip_runtime.h>
#include <math.h>
#include <stdint.h>

#define LOG2E 1.44269504088896340736f
#define TPS 8      // j-tiles per super-step (18 KB LDS)
#define JS  8      // j-range splits (157x8 blocks -> ~4.9 waves/SIMD)
#define ITW 4      // i-tiles per wave (64 rows): 1 staged B fragment feeds 4 MFMAs
#define CUT -16.0f // skip exp when ALL 256 tile entries have log2(K) < -16

typedef _Float16 f16x8 __attribute__((ext_vector_type(8)));
typedef float f32x4 __attribute__((ext_vector_type(4)));

__device__ __forceinline__ float softplus_f(float t) {
    return (t > 20.0f) ? t : log1pf(expf(t));
}

// global -> LDS direct DMA, 16 B/lane. lds base must be wave-uniform; HW adds lane*16.
#define GLDS16(g, l)                                                     \
    __builtin_amdgcn_global_load_lds(                                    \
        (const __attribute__((address_space(1))) uint32_t*)(const void*)(g), \
        (__attribute__((address_space(3))) uint32_t*)(void*)(l), 16, 0, 0)

// ---------------- pass 1: fragment-linear f16 B workspace + zero out/counters ----------------
// Tile jt, fragment pos l = q*16+m holds c[j=jt*16+m][k=q*8..q*8+7] as f16 ->
// wave B-load = base + lane*16 B (dense, DMA-compatible).
// sbG[j] = { -0.5*log2e*|c_j|^2, beta_j }; beta=0 on padding kills pad cols.
// Also zeroes out[] (atomicAdd target) and cnt[] (finisher counters).
__global__ void prep_c_kernel(const float* __restrict__ c,
                              const float* __restrict__ beta,
                              _Float16* __restrict__ chiF,
                              float2* __restrict__ sbG,
                              float* __restrict__ out,
                              unsigned* __restrict__ cnt,
                              int M, int Mp, int N, int ngroups) {
    int tid = blockIdx.x * blockDim.x + threadIdx.x;
    if (tid < N) out[tid] = 0.0f;
    if (tid < ngroups) cnt[tid] = 0u;

    int j = tid >> 2, q = tid & 3;
    if (j >= Mp) return;
    int jt = j >> 4, m = j & 15;
    size_t fo = (size_t)jt * 512 + (size_t)(q * 16 + m) * 8;   // halves

    float ssq = 0.0f;
    _Float16 hi[8];
    if (j < M) {
        const float4* cp = (const float4*)(c + (size_t)j * 32 + q * 8);
        float4 a = cp[0], b = cp[1];
        float vv[8] = {a.x, a.y, a.z, a.w, b.x, b.y, b.z, b.w};
#pragma unroll
        for (int t = 0; t < 8; ++t) {
            float f = vv[t];
            ssq = fmaf(f, f, ssq);
            hi[t] = (_Float16)f;
        }
    } else {
#pragma unroll
        for (int t = 0; t < 8; ++t) hi[t] = (_Float16)0.0f;
    }
    ssq += __shfl_xor(ssq, 1, 4);       // |c_j|^2 over the 4 q-threads
    ssq += __shfl_xor(ssq, 2, 4);

    *(f16x8*)(chiF + fo) = *(const f16x8*)hi;
    if (q == 0)
        sbG[j] = (j < M) ? make_float2(-0.5f * LOG2E * ssq, beta[j])
                         : make_float2(0.0f, 0.0f);
}

// ---------------- main: LDS-staged MFMA RBF matvec, exp-skip, fused softplus ----------------
// Block = 4 waves; wave w owns FOUR i-tiles (64 rows, group g = bx*4+w); one staged
// B fragment feeds 4 MFMAs (quarters the LDS-read cost per pair). blockIdx.y picks
// an eighth of the j-tiles. Exp-skip: wave-uniform __any branch elides the
// 4x v_exp_f32 (16cy each) + fma block on ~86% of 16x16 tiles (CUT=-16: dropped
// mass ~5e-5 << 1.39e-2 threshold; round-7 absmax 0.0039 confirms margin).
// Finisher: last j-split block per group applies softplus in-place (counter
// protocol, device-scope) — no third kernel.
// C layout (m89): col = lane&15, row = (lane>>4)*4 + reg.
__global__ __launch_bounds__(256) void krr_mfma_lds_kernel(
    const float* __restrict__ x,
    const _Float16* __restrict__ chiF,
    const float2* __restrict__ sbG,
    float* __restrict__ out,
    unsigned* __restrict__ cnt,
    int N, int steps, int ngroups)
{
    __shared__ f16x8 chiS[2][TPS][64];                // 16 KB
    __shared__ __align__(16) float2 sbS[2][TPS * 16]; // 2 KB

    const int wave = threadIdx.x >> 6;
    const int lane = threadIdx.x & 63;
    const int m    = lane & 15;
    const int quad = lane >> 4;

    const int g  = blockIdx.x * 4 + wave;    // 64-row group
    const int s0 = blockIdx.y * steps;       // this block's super-step range

    // ---- four A fragments (rows g*64 + f*16 + m), pre-scaled by log2e ----
    f16x8 ahi[ITW];
    float air[ITW][4];
#pragma unroll
    for (int f = 0; f < ITW; ++f) {
        int row = g * 64 + f * 16 + m;
        int rc = (row < N) ? row : (N - 1);          // clamp load; stores guarded
        const float4* xp = (const float4*)(x + (size_t)rc * 32 + quad * 8);
        float4 v0 = xp[0], v1 = xp[1];
        float p = v0.x * v0.x + v0.y * v0.y + v0.z * v0.z + v0.w * v0.w
                + v1.x * v1.x + v1.y * v1.y + v1.z * v1.z + v1.w * v1.w;
        p += __shfl_xor(p, 16, 64);
        p += __shfl_xor(p, 32, 64);                  // |x_row|^2 over all quads
        float ai_m = -0.5f * LOG2E * p;
        float vv[8] = {v0.x, v0.y, v0.z, v0.w, v1.x, v1.y, v1.z, v1.w};
#pragma unroll
        for (int t = 0; t < 8; ++t)
            ahi[f][t] = (_Float16)(vv[t] * LOG2E);
#pragma unroll
        for (int r = 0; r < 4; ++r)
            air[f][r] = __shfl(ai_m, quad * 4 + r, 16);  // a_i for C row quad*4+r
    }

    // ---- staging: 8 chi chunks (2/wave) + 1 sb chunk per step ----
    auto stage = [&](int s, int b) {
        const _Float16* base = chiF + (size_t)(s0 + s) * TPS * 512;
#pragma unroll
        for (int ch = wave; ch < TPS; ch += 4)
            GLDS16(base + (size_t)ch * 512 + (size_t)lane * 8, &chiS[b][ch][0]);
        if (wave == 0)
            GLDS16((const char*)(sbG + (size_t)(s0 + s) * (TPS * 16)) + (size_t)lane * 16,
                   &sbS[b][0]);
    };

    stage(0, 0);
    float oacc[ITW][4];
#pragma unroll
    for (int f = 0; f < ITW; ++f)
#pragma unroll
        for (int r = 0; r < 4; ++r) oacc[f][r] = 0.0f;

    for (int s = 0; s < steps; ++s) {
        const int b = s & 1;
        __syncthreads();                 // drains stage(s) DMA; guards buffer b^1 reuse
        if (s + 1 < steps) stage(s + 1, b ^ 1);

#pragma unroll
        for (int t = 0; t < TPS; ++t) {
            f16x8 bhi = chiS[b][t][lane];             // ds_read_b128, lane-linear
            float2 s2 = sbS[b][t * 16 + m];           // {s_j, beta_j}, broadcast
#pragma unroll
            for (int f = 0; f < ITW; ++f) {
                f32x4 acc;
#pragma unroll
                for (int r = 0; r < 4; ++r) acc[r] = air[f][r] + s2.x;  // a_i+s_j in C
                acc = __builtin_amdgcn_mfma_f32_16x16x32_f16(ahi[f], bhi, acc, 0, 0, 0);
                float mx = fmaxf(fmaxf(acc[0], acc[1]), fmaxf(acc[2], acc[3]));
                if (__any(mx > CUT)) {                // wave-uniform skip branch
#pragma unroll
                    for (int r = 0; r < 4; ++r)
                        oacc[f][r] = fmaf(s2.y, __builtin_amdgcn_exp2f(acc[r]), oacc[f][r]);
                }
            }
        }
    }

    // ---- reduce over 16 cols (lane bits 0..3), atomic partial-sum ----
#pragma unroll
    for (int f = 0; f < ITW; ++f) {
        const int rowbase = g * 64 + f * 16;
#pragma unroll
        for (int r = 0; r < 4; ++r) {
            float v = oacc[f][r];
            v += __shfl_xor(v, 1, 64);
            v += __shfl_xor(v, 2, 64);
            v += __shfl_xor(v, 4, 64);
            v += __shfl_xor(v, 8, 64);
            if (m == r) {
                int row = rowbase + quad * 4 + r;
                if (row < N) atomicAdd(out + row, v);
            }
        }
    }

    // ---- finisher: last split-block for group g applies softplus to its 64 rows ----
    if (g < ngroups) {
        __threadfence();                              // partials visible before count
        int last = 0;
        if (lane == 0) {
            unsigned old = atomicAdd(cnt + g, 1u);
            last = (old == (unsigned)(JS - 1));
        }
        last = __shfl(last, 0, 64);
        if (last) {
            __threadfence();
            int row = g * 64 + lane;
            if (row < N) {
                float v = __hip_atomic_load(out + row, __ATOMIC_RELAXED,
                                            __HIP_MEMORY_SCOPE_AGENT);
                out[row] = softplus_f(v);
            }
        }
    }
}

// ---------------- fallback path (ws too small): round-1 VALU kernel ----------------
#define CHUNK_MAX 512
__global__ void zero_out_kernel(float* __restrict__ out, int n) {
    int i = blockIdx.x * blockDim.x + threadIdx.x;
    if (i < n) out[i] = 0.0f;
}
__global__ void softplus_kernel(float* __restrict__ out, int n) {
    int i = blockIdx.x * blockDim.x + threadIdx.x;
    if (i < n) out[i] = softplus_f(out[i]);
}
__global__ __launch_bounds__(64, 4) void krr_partial_kernel(
    const float* __restrict__ x, const float* __restrict__ c,
    const float* __restrict__ beta, float* __restrict__ out,
    int N, int M, int chunk)
{
    __shared__ float2 sw[CHUNK_MAX];
    const int lane = threadIdx.x;
    const int j0 = blockIdx.y * chunk;
    const int j1 = min(M, j0 + chunk);
    for (int j = j0 + lane; j < j1; j += 64) {
        const float4* cr = (const float4*)(c + (size_t)j * 32);
        float s = 0.0f;
#pragma unroll
        for (int q = 0; q < 8; ++q) {
            float4 v = cr[q];
            s = fmaf(v.x, v.x, s); s = fmaf(v.y, v.y, s);
            s = fmaf(v.z, v.z, s); s = fmaf(v.w, v.w, s);
        }
        sw[j - j0] = make_float2(-0.5f * LOG2E * s, beta[j]);
    }
    __syncthreads();
    const int i = blockIdx.x * 64 + lane;
    const bool valid = (i < N);
    const float4* xrow = (const float4*)(x + (size_t)(valid ? i : 0) * 32);
    float xr[32]; float xsq = 0.0f;
#pragma unroll
    for (int q = 0; q < 8; ++q) {
        float4 v = xrow[q];
        xsq = fmaf(v.x, v.x, xsq); xsq = fmaf(v.y, v.y, xsq);
        xsq = fmaf(v.z, v.z, xsq); xsq = fmaf(v.w, v.w, xsq);
        xr[4*q+0] = v.x * LOG2E; xr[4*q+1] = v.y * LOG2E;
        xr[4*q+2] = v.z * LOG2E; xr[4*q+3] = v.w * LOG2E;
    }
    const float ai = -0.5f * LOG2E * xsq;
    float acc = 0.0f;
#pragma unroll 2
    for (int j = j0; j < j1; ++j) {
        const float4* cr = (const float4*)(c + (size_t)j * 32);
        const float2 s2 = sw[j - j0];
        float d = ai + s2.x;
#pragma unroll
        for (int q = 0; q < 8; ++q) {
            float4 v = cr[q];
            d = fmaf(xr[4*q+0], v.x, d); d = fmaf(xr[4*q+1], v.y, d);
            d = fmaf(xr[4*q+2], v.z, d); d = fmaf(xr[4*q+3], v.w, d);
        }
        acc = fmaf(s2.y, __builtin_amdgcn_exp2f(d), acc);
    }
    if (valid) atomicAdd(out + i, acc);
}

extern "C" void kernel_launch(void* const* d_in, const int* in_sizes, int n_in,
                              void* d_out, int out_size, void* d_ws, size_t ws_size,
                              hipStream_t stream) {
    const float* x    = (const float*)d_in[0];   // (N, 32)
    const float* c    = (const float*)d_in[1];   // (M, 32)
    const float* beta = (const float*)d_in[2];   // (M,)
    float* out = (float*)d_out;                  // (N,)

    const int N = out_size;                      // 40000
    const int M = in_sizes[2];                   // 4000
    const int JT = (M + 15) / 16;                // 250 j-tiles
    const int SPAN = TPS * JS;                   // tile granularity: 64
    const int JTS = ((JT + SPAN - 1) / SPAN) * SPAN;  // padded: 256
    const int steps = JTS / SPAN;                // super-steps per j-split: 4
    const int Mp = JTS * 16;                     // 4096 padded cols
    const int ngroups = (N + 63) / 64;           // 625 64-row groups

    // ws: chiF (JTS*512 halves) | sbG (Mp float2) | cnt (ngroups u32) ~ 290 KB
    const size_t need = (size_t)JTS * 1024 + (size_t)Mp * 8 + (size_t)ngroups * 4;

    if (ws_size >= need) {
        _Float16* chiF = (_Float16*)d_ws;
        float2*   sbG  = (float2*)(chiF + (size_t)JTS * 512);
        unsigned* cnt  = (unsigned*)(sbG + Mp);

        int prep_threads = (Mp * 4 > N) ? Mp * 4 : N;
        prep_c_kernel<<<dim3((prep_threads + 255) / 256), dim3(256), 0, stream>>>(
            c, beta, chiF, sbG, out, cnt, M, Mp, N, ngroups);

        const int bx = (ngroups + 3) / 4;            // 157 blocks x 4 waves
        krr_mfma_lds_kernel<<<dim3(bx, JS), dim3(256), 0, stream>>>(
            x, chiF, sbG, out, cnt, N, steps, ngroups);
    } else {
        zero_out_kernel<<<dim3((N + 255) / 256), dim3(256), 0, stream>>>(out, N);
        int jc = (M + CHUNK_MAX - 1) / CHUNK_MAX;
        if (jc < 8) jc = 8;
        int chunk = (M + jc - 1) / jc;
        dim3 grid((N + 63) / 64, jc);
        krr_partial_kernel<<<grid, dim3(64), 0, stream>>>(x, c, beta, out, N, M, chunk);
        softplus_kernel<<<dim3((N + 255) / 256), dim3(256), 0, stream>>>(out, N);
    }
}

// Round 9
// 91.172 us; speedup vs baseline: 1.8267x; 1.8267x over previous
//
#include <hip/hip_runtime.h>
#include <math.h>
#include <stdint.h>

#define LOG2E 1.44269504088896340736f
#define TPS 8      // j-tiles per super-step (18 KB LDS -> 8 blocks/CU capacity)
#define JS  4      // j-range splits (313x4 blocks -> ~4.9 waves/SIMD)
#define CUT -16.0f // skip exp when ALL 256 tile entries have log2(K) < -16
                   // (K < 1.5e-5; dropped mass ~5e-5; measured absmax 0.0039 -> 3.5x margin)

// ROUND-8 LESSON (do not re-add): a per-wave __threadfence() finisher forced
// device-scope L2 writebacks across XCDs -> B-stream refetched from HBM
// (FETCH 6->21 MB), main kernel 3x slower. Separate softplus pass is cheaper.

typedef _Float16 f16x8 __attribute__((ext_vector_type(8)));
typedef float f32x4 __attribute__((ext_vector_type(4)));

__device__ __forceinline__ float softplus_f(float t) {
    return (t > 20.0f) ? t : log1pf(expf(t));
}

// global -> LDS direct DMA, 16 B/lane. lds base must be wave-uniform; HW adds lane*16.
#define GLDS16(g, l)                                                     \
    __builtin_amdgcn_global_load_lds(                                    \
        (const __attribute__((address_space(1))) uint32_t*)(const void*)(g), \
        (__attribute__((address_space(3))) uint32_t*)(void*)(l), 16, 0, 0)

// ---------------- pass 1: fragment-linear f16 B workspace + out zero-init ----------------
// Tile jt, fragment pos l = q*16+m holds c[j=jt*16+m][k=q*8..q*8+7] as f16 ->
// wave B-load = base + lane*16 B (dense, DMA-compatible).
// sbG[j] = { -0.5*log2e*|c_j|^2, beta_j }; beta=0 on padding kills pad cols.
// Also zeroes out[] (atomicAdd target for the j-split main kernel).
__global__ void prep_c_kernel(const float* __restrict__ c,
                              const float* __restrict__ beta,
                              _Float16* __restrict__ chiF,
                              float2* __restrict__ sbG,
                              float* __restrict__ out,
                              int M, int Mp, int N) {
    int tid = blockIdx.x * blockDim.x + threadIdx.x;
    if (tid < N) out[tid] = 0.0f;

    int j = tid >> 2, q = tid & 3;
    if (j >= Mp) return;
    int jt = j >> 4, m = j & 15;
    size_t fo = (size_t)jt * 512 + (size_t)(q * 16 + m) * 8;   // halves

    float ssq = 0.0f;
    _Float16 hi[8];
    if (j < M) {
        const float4* cp = (const float4*)(c + (size_t)j * 32 + q * 8);
        float4 a = cp[0], b = cp[1];
        float vv[8] = {a.x, a.y, a.z, a.w, b.x, b.y, b.z, b.w};
#pragma unroll
        for (int t = 0; t < 8; ++t) {
            float f = vv[t];
            ssq = fmaf(f, f, ssq);
            hi[t] = (_Float16)f;
        }
    } else {
#pragma unroll
        for (int t = 0; t < 8; ++t) hi[t] = (_Float16)0.0f;
    }
    ssq += __shfl_xor(ssq, 1, 4);       // |c_j|^2 over the 4 q-threads
    ssq += __shfl_xor(ssq, 2, 4);

    *(f16x8*)(chiF + fo) = *(const f16x8*)hi;
    if (q == 0)
        sbG[j] = (j < M) ? make_float2(-0.5f * LOG2E * ssq, beta[j])
                         : make_float2(0.0f, 0.0f);
}

// ---------------- main: LDS-staged MFMA RBF matvec with exp-skip ----------------
// Block = 4 waves; wave w owns TWO i-tiles (rows g*32..g*32+31, g = bx*4+w), so
// each staged B fragment feeds 2 MFMAs. blockIdx.y picks a quarter of the j-tiles.
// Exp-skip: a tile needs exp only if any entry has acc > CUT (~6-12% of tiles).
// Wave-uniform __any branch skips the 4x v_exp_f32 (16 cy each) + fma block.
// C layout (m89): col = lane&15, row = (lane>>4)*4 + reg.
__global__ __launch_bounds__(256) void krr_mfma_lds_kernel(
    const float* __restrict__ x,
    const _Float16* __restrict__ chiF,
    const float2* __restrict__ sbG,
    float* __restrict__ out,
    int N, int steps)             // super-steps per j-split
{
    __shared__ f16x8 chiS[2][TPS][64];                // 16 KB
    __shared__ __align__(16) float2 sbS[2][TPS * 16]; // 2 KB

    const int wave = threadIdx.x >> 6;
    const int lane = threadIdx.x & 63;
    const int m    = lane & 15;
    const int quad = lane >> 4;

    const int g  = blockIdx.x * 4 + wave;    // 32-row group
    const int s0 = blockIdx.y * steps;       // this block's super-step range

    // ---- two A fragments (rows g*32+m and g*32+16+m), pre-scaled by log2e ----
    f16x8 ahi1, ahi2;
    float air1[4], air2[4];
    {
        int rows[2] = {g * 32 + m, g * 32 + 16 + m};
        f16x8* ah[2] = {&ahi1, &ahi2};
        float* ar[2] = {air1, air2};
#pragma unroll
        for (int f = 0; f < 2; ++f) {
            int rc = (rows[f] < N) ? rows[f] : (N - 1);  // clamp load; stores are guarded
            const float4* xp = (const float4*)(x + (size_t)rc * 32 + quad * 8);
            float4 v0 = xp[0], v1 = xp[1];
            float p = v0.x * v0.x + v0.y * v0.y + v0.z * v0.z + v0.w * v0.w
                    + v1.x * v1.x + v1.y * v1.y + v1.z * v1.z + v1.w * v1.w;
            p += __shfl_xor(p, 16, 64);
            p += __shfl_xor(p, 32, 64);               // |x_row|^2 over all quads
            float ai_m = -0.5f * LOG2E * p;
            float vv[8] = {v0.x, v0.y, v0.z, v0.w, v1.x, v1.y, v1.z, v1.w};
#pragma unroll
            for (int t = 0; t < 8; ++t)
                (*ah[f])[t] = (_Float16)(vv[t] * LOG2E);
#pragma unroll
            for (int r = 0; r < 4; ++r)
                ar[f][r] = __shfl(ai_m, quad * 4 + r, 16);  // a_i for C row quad*4+r
        }
    }

    // ---- staging: 8 chi chunks (2/wave) + 1 sb chunk per step ----
    auto stage = [&](int s, int b) {
        const _Float16* base = chiF + (size_t)(s0 + s) * TPS * 512;
#pragma unroll
        for (int ch = wave; ch < TPS; ch += 4)
            GLDS16(base + (size_t)ch * 512 + (size_t)lane * 8, &chiS[b][ch][0]);
        if (wave == 0)
            GLDS16((const char*)(sbG + (size_t)(s0 + s) * (TPS * 16)) + (size_t)lane * 16,
                   &sbS[b][0]);
    };

    stage(0, 0);
    float out1[4] = {0.0f, 0.0f, 0.0f, 0.0f};
    float out2[4] = {0.0f, 0.0f, 0.0f, 0.0f};

    for (int s = 0; s < steps; ++s) {
        const int b = s & 1;
        __syncthreads();                 // drains stage(s) DMA; guards buffer b^1 reuse
        if (s + 1 < steps) stage(s + 1, b ^ 1);

#pragma unroll
        for (int t = 0; t < TPS; ++t) {
            f16x8 bhi = chiS[b][t][lane];             // ds_read_b128, lane-linear
            float2 s2 = sbS[b][t * 16 + m];           // {s_j, beta_j}, broadcast
            f32x4 acc1, acc2;
#pragma unroll
            for (int r = 0; r < 4; ++r) {
                acc1[r] = air1[r] + s2.x;             // fold a_i + s_j into C init
                acc2[r] = air2[r] + s2.x;
            }
            acc1 = __builtin_amdgcn_mfma_f32_16x16x32_f16(ahi1, bhi, acc1, 0, 0, 0);
            acc2 = __builtin_amdgcn_mfma_f32_16x16x32_f16(ahi2, bhi, acc2, 0, 0, 0);

            float mx1 = fmaxf(fmaxf(acc1[0], acc1[1]), fmaxf(acc1[2], acc1[3]));
            float mx2 = fmaxf(fmaxf(acc2[0], acc2[1]), fmaxf(acc2[2], acc2[3]));
            if (__any(mx1 > CUT)) {                   // wave-uniform: s_cbranch skip
#pragma unroll
                for (int r = 0; r < 4; ++r)
                    out1[r] = fmaf(s2.y, __builtin_amdgcn_exp2f(acc1[r]), out1[r]);
            }
            if (__any(mx2 > CUT)) {
#pragma unroll
                for (int r = 0; r < 4; ++r)
                    out2[r] = fmaf(s2.y, __builtin_amdgcn_exp2f(acc2[r]), out2[r]);
            }
        }
    }

    // ---- reduce over 16 cols (lane bits 0..3), atomic partial-sum ----
    float* oas[2] = {out1, out2};
#pragma unroll
    for (int f = 0; f < 2; ++f) {
        const int rowbase = g * 32 + f * 16;
#pragma unroll
        for (int r = 0; r < 4; ++r) {
            float v = oas[f][r];
            v += __shfl_xor(v, 1, 64);
            v += __shfl_xor(v, 2, 64);
            v += __shfl_xor(v, 4, 64);
            v += __shfl_xor(v, 8, 64);
            if (m == r) {
                int row = rowbase + quad * 4 + r;
                if (row < N) atomicAdd(out + row, v);
            }
        }
    }
}

// ---------------- pass 3: softplus over accumulated partials ----------------
__global__ void softplus_kernel(float* __restrict__ out, int n) {
    int i = blockIdx.x * blockDim.x + threadIdx.x;
    if (i < n) out[i] = softplus_f(out[i]);
}

// ---------------- fallback path (ws too small): round-1 VALU kernel ----------------
#define CHUNK_MAX 512
__global__ void zero_out_kernel(float* __restrict__ out, int n) {
    int i = blockIdx.x * blockDim.x + threadIdx.x;
    if (i < n) out[i] = 0.0f;
}
__global__ __launch_bounds__(64, 4) void krr_partial_kernel(
    const float* __restrict__ x, const float* __restrict__ c,
    const float* __restrict__ beta, float* __restrict__ out,
    int N, int M, int chunk)
{
    __shared__ float2 sw[CHUNK_MAX];
    const int lane = threadIdx.x;
    const int j0 = blockIdx.y * chunk;
    const int j1 = min(M, j0 + chunk);
    for (int j = j0 + lane; j < j1; j += 64) {
        const float4* cr = (const float4*)(c + (size_t)j * 32);
        float s = 0.0f;
#pragma unroll
        for (int q = 0; q < 8; ++q) {
            float4 v = cr[q];
            s = fmaf(v.x, v.x, s); s = fmaf(v.y, v.y, s);
            s = fmaf(v.z, v.z, s); s = fmaf(v.w, v.w, s);
        }
        sw[j - j0] = make_float2(-0.5f * LOG2E * s, beta[j]);
    }
    __syncthreads();
    const int i = blockIdx.x * 64 + lane;
    const bool valid = (i < N);
    const float4* xrow = (const float4*)(x + (size_t)(valid ? i : 0) * 32);
    float xr[32]; float xsq = 0.0f;
#pragma unroll
    for (int q = 0; q < 8; ++q) {
        float4 v = xrow[q];
        xsq = fmaf(v.x, v.x, xsq); xsq = fmaf(v.y, v.y, xsq);
        xsq = fmaf(v.z, v.z, xsq); xsq = fmaf(v.w, v.w, xsq);
        xr[4*q+0] = v.x * LOG2E; xr[4*q+1] = v.y * LOG2E;
        xr[4*q+2] = v.z * LOG2E; xr[4*q+3] = v.w * LOG2E;
    }
    const float ai = -0.5f * LOG2E * xsq;
    float acc = 0.0f;
#pragma unroll 2
    for (int j = j0; j < j1; ++j) {
        const float4* cr = (const float4*)(c + (size_t)j * 32);
        const float2 s2 = sw[j - j0];
        float d = ai + s2.x;
#pragma unroll
        for (int q = 0; q < 8; ++q) {
            float4 v = cr[q];
            d = fmaf(xr[4*q+0], v.x, d); d = fmaf(xr[4*q+1], v.y, d);
            d = fmaf(xr[4*q+2], v.z, d); d = fmaf(xr[4*q+3], v.w, d);
        }
        acc = fmaf(s2.y, __builtin_amdgcn_exp2f(d), acc);
    }
    if (valid) atomicAdd(out + i, acc);
}

extern "C" void kernel_launch(void* const* d_in, const int* in_sizes, int n_in,
                              void* d_out, int out_size, void* d_ws, size_t ws_size,
                              hipStream_t stream) {
    const float* x    = (const float*)d_in[0];   // (N, 32)
    const float* c    = (const float*)d_in[1];   // (M, 32)
    const float* beta = (const float*)d_in[2];   // (M,)
    float* out = (float*)d_out;                  // (N,)

    const int N = out_size;                      // 40000
    const int M = in_sizes[2];                   // 4000
    const int JT = (M + 15) / 16;                // 250 j-tiles
    const int SPAN = TPS * JS;                   // tile granularity: 32
    const int JTS = ((JT + SPAN - 1) / SPAN) * SPAN;  // padded: 256
    const int steps = JTS / SPAN;                // super-steps per j-split: 8
    const int Mp = JTS * 16;                     // 4096 padded cols

    // ws: chiF (JTS*512 halves, fragment-linear) | sbG (Mp float2)  ~ 288 KB
    const size_t need = (size_t)JTS * 1024 + (size_t)Mp * 8;

    if (ws_size >= need) {
        _Float16* chiF = (_Float16*)d_ws;
        float2*   sbG  = (float2*)(chiF + (size_t)JTS * 512);

        int prep_threads = (Mp * 4 > N) ? Mp * 4 : N;
        prep_c_kernel<<<dim3((prep_threads + 255) / 256), dim3(256), 0, stream>>>(
            c, beta, chiF, sbG, out, M, Mp, N);

        const int groups = (N + 31) / 32;            // 1250 32-row groups
        const int bx = (groups + 3) / 4;             // 313 blocks x 4 waves
        krr_mfma_lds_kernel<<<dim3(bx, JS), dim3(256), 0, stream>>>(
            x, chiF, sbG, out, N, steps);

        softplus_kernel<<<dim3((N + 255) / 256), dim3(256), 0, stream>>>(out, N);
    } else {
        zero_out_kernel<<<dim3((N + 255) / 256), dim3(256), 0, stream>>>(out, N);
        int jc = (M + CHUNK_MAX - 1) / CHUNK_MAX;
        if (jc < 8) jc = 8;
        int chunk = (M + jc - 1) / jc;
        dim3 grid((N + 63) / 64, jc);
        krr_partial_kernel<<<grid, dim3(64), 0, stream>>>(x, c, beta, out, N, M, chunk);
        softplus_kernel<<<dim3((N + 255) / 256), dim3(256), 0, stream>>>(out, N);
    }
}